// Round 1
// baseline (404.639 us; speedup 1.0000x reference)
//
#include <hip/hip_runtime.h>
#include <hip/hip_bf16.h>

typedef float f32x4 __attribute__((ext_vector_type(4)));
typedef short s16x8 __attribute__((ext_vector_type(8)));

#define LOG2E 1.4426950408889634f
#define NEGINF (-1e30f)

__device__ __forceinline__ unsigned short f2bf(float f) {
    __hip_bfloat16 h = __float2bfloat16(f);
    unsigned short u;
    __builtin_memcpy(&u, &h, 2);
    return u;
}

// ---------------------------------------------------------------------------
// Pre-kernel: fused[wh][c][r] = (mask[w][c][r] + bias_table[rel_index[c][r]][h]) * log2(e)
// Layout: [512][49][52] f32 (r-stride padded to 52 so r0 = 16*mr + 4*g is 16B-aligned)
// ---------------------------------------------------------------------------
__global__ void fuse_bias_mask(const float* __restrict__ bias_table,
                               const float* __restrict__ mask,
                               const int*   __restrict__ rel_index,
                               float*       __restrict__ fused) {
    int tid = blockIdx.x * 256 + threadIdx.x;
    const int total = 512 * 2401;
    if (tid >= total) return;
    int wh  = tid / 2401;
    int rem = tid - wh * 2401;          // = c*49 + r
    int c   = rem / 49;
    int w = wh >> 3, h = wh & 7;
    int idx = rel_index[rem];
    float v = (mask[w * 2401 + rem] + bias_table[idx * 8 + h]) * LOG2E;
    fused[((long)wh * 49 + c) * 52 + (rem - c * 49)] = v;
}

// ---------------------------------------------------------------------------
// Main kernel: 1 block = 1 window-batch b; 4 waves; each wave does 2 heads.
// Per head: S = X_h X_h^T via hi/lo-split bf16 MFMA (D[r=key][c=query], S symmetric
// so transposed orientation is free; bias/mask added transposed), in-register
// wave softmax over keys, normalized P -> swizzled per-wave LDS tile (bf16),
// then O = P V via bf16 MFMA with V frags loaded (strided) from global.
// No __syncthreads anywhere (P is wave-private).
// ---------------------------------------------------------------------------
template<bool FUSED>
__global__ __launch_bounds__(256, 2)
void win_attn(const float* __restrict__ x,
              const float* __restrict__ bias_table,
              const float* __restrict__ mask,
              const int*   __restrict__ rel_index,
              const float* __restrict__ fused,
              float*       __restrict__ out) {
    __shared__ char Plds[4][8192];      // per-wave P tile: [64 c][64 j] bf16, XOR-swizzled
    const int tid  = threadIdx.x;
    const int wav  = tid >> 6;
    const int lane = tid & 63;
    const int li   = lane & 15;
    const int g    = lane >> 4;
    const int b    = blockIdx.x;
    const int w    = b & 63;            // b = img*64 + w
    char* P = &Plds[wav][0];
    const float scale2 = 0.17677669529663689f * LOG2E;  // hd^-0.5 * log2(e)

    const float* xb = x + (long)b * (49 * 256);

    for (int hh = 0; hh < 2; ++hh) {
        const int h = wav * 2 + hh;
        const float* xh = xb + h * 32;

        // ---- QK fragments of X_h: rows 16t+li, cols g*8..g*8+7 (hi/lo bf16) ----
        s16x8 Fh[4], Fl[4];
        #pragma unroll
        for (int t = 0; t < 4; ++t) {
            int row = t * 16 + li;
            float f[8];
            if (row < 49) {
                const f32x4* p = (const f32x4*)(xh + row * 256 + g * 8);
                f32x4 v0 = p[0], v1 = p[1];
                f[0]=v0.x; f[1]=v0.y; f[2]=v0.z; f[3]=v0.w;
                f[4]=v1.x; f[5]=v1.y; f[6]=v1.z; f[7]=v1.w;
            } else {
                #pragma unroll
                for (int j = 0; j < 8; ++j) f[j] = 0.f;
            }
            s16x8 hi, lo;
            #pragma unroll
            for (int j = 0; j < 8; ++j) {
                unsigned u = __float_as_uint(f[j]);
                hi[j] = (short)(u >> 16);                       // truncated high bf16
                float rm = f[j] - __uint_as_float(u & 0xFFFF0000u);
                lo[j] = (short)f2bf(rm);                        // RNE residual
            }
            Fh[t] = hi; Fl[t] = lo;
        }

        // ---- V fragments (PV B-operand): col d=li+16nd, k-slots j=32kt+8g+jj ----
        // (issued early so the strided loads hide under QK MFMAs + softmax)
        s16x8 Vf[2][2];
        #pragma unroll
        for (int nd = 0; nd < 2; ++nd)
            #pragma unroll
            for (int kt = 0; kt < 2; ++kt) {
                int d = li + 16 * nd;
                s16x8 vv;
                #pragma unroll
                for (int jj = 0; jj < 8; ++jj) {
                    int j = 32 * kt + 8 * g + jj;
                    float v = (j < 49) ? xh[j * 256 + d] : 0.f;
                    vv[jj] = (short)f2bf(v);
                }
                Vf[nd][kt] = vv;
            }

        // ---- S = X X^T, hi/lo split: D[r][c], r=key (A rows), c=query (B cols) ----
        f32x4 acc[4][4];
        #pragma unroll
        for (int mr = 0; mr < 4; ++mr)
            #pragma unroll
            for (int nc = 0; nc < 4; ++nc)
                acc[mr][nc] = f32x4{0.f, 0.f, 0.f, 0.f};
        #pragma unroll
        for (int mr = 0; mr < 4; ++mr)
            #pragma unroll
            for (int nc = 0; nc < 4; ++nc) {
                f32x4 a = acc[mr][nc];
                a = __builtin_amdgcn_mfma_f32_16x16x32_bf16(Fh[mr], Fh[nc], a, 0, 0, 0);
                a = __builtin_amdgcn_mfma_f32_16x16x32_bf16(Fh[mr], Fl[nc], a, 0, 0, 0);
                a = __builtin_amdgcn_mfma_f32_16x16x32_bf16(Fl[mr], Fh[nc], a, 0, 0, 0);
                acc[mr][nc] = a;
            }

        // ---- logits + softmax (C/D layout: c = li, r = 4g + reg + 16mr) ----
        const int wh = w * 8 + h;
        #pragma unroll
        for (int nc = 0; nc < 4; ++nc) {
            int c = li + 16 * nc;
            int cidx = min(c, 48);                 // c>=49: garbage rows, clamp (finite)
            if (FUSED) {
                const float* fb = fused + ((long)wh * 49 + cidx) * 52;
                #pragma unroll
                for (int mr = 0; mr < 3; ++mr) {
                    f32x4 t = *(const f32x4*)(fb + 16 * mr + 4 * g);
                    #pragma unroll
                    for (int i = 0; i < 4; ++i)
                        acc[mr][nc][i] = acc[mr][nc][i] * scale2 + t[i];
                }
                float t48 = fb[48];
                acc[3][nc][0] = (g == 0) ? acc[3][nc][0] * scale2 + t48 : NEGINF;
                acc[3][nc][1] = NEGINF; acc[3][nc][2] = NEGINF; acc[3][nc][3] = NEGINF;
            } else {
                const int base = cidx * 49;
                #pragma unroll
                for (int mr = 0; mr < 3; ++mr)
                    #pragma unroll
                    for (int i = 0; i < 4; ++i) {
                        int r = 16 * mr + 4 * g + i;
                        float bm = (mask[w * 2401 + base + r]
                                    + bias_table[rel_index[base + r] * 8 + h]) * LOG2E;
                        acc[mr][nc][i] = acc[mr][nc][i] * scale2 + bm;
                    }
                float bm48 = (mask[w * 2401 + base + 48]
                              + bias_table[rel_index[base + 48] * 8 + h]) * LOG2E;
                acc[3][nc][0] = (g == 0) ? acc[3][nc][0] * scale2 + bm48 : NEGINF;
                acc[3][nc][1] = NEGINF; acc[3][nc][2] = NEGINF; acc[3][nc][3] = NEGINF;
            }
            // row max over 64 keys: 16 in-lane + lane-groups via shfl_xor 16/32
            float m = NEGINF;
            #pragma unroll
            for (int mr = 0; mr < 4; ++mr)
                #pragma unroll
                for (int i = 0; i < 4; ++i) m = fmaxf(m, acc[mr][nc][i]);
            m = fmaxf(m, __shfl_xor(m, 16));
            m = fmaxf(m, __shfl_xor(m, 32));
            // exp2 & sum (log2e pre-folded); invalid keys -> exp2(-1e30)=0
            float s = 0.f;
            #pragma unroll
            for (int mr = 0; mr < 4; ++mr)
                #pragma unroll
                for (int i = 0; i < 4; ++i) {
                    float p = __builtin_amdgcn_exp2f(acc[mr][nc][i] - m);
                    acc[mr][nc][i] = p;
                    s += p;
                }
            s += __shfl_xor(s, 16);
            s += __shfl_xor(s, 32);
            float sinv = __builtin_amdgcn_rcpf(s);
            // normalized P row -> LDS bf16, byte ^= ((c&7)<<4) swizzle
            char* rowp = P + c * 128;
            unsigned sw = ((unsigned)(c & 7)) << 4;
            #pragma unroll
            for (int mr = 0; mr < 4; ++mr) {
                unsigned short b0 = f2bf(acc[mr][nc][0] * sinv);
                unsigned short b1 = f2bf(acc[mr][nc][1] * sinv);
                unsigned short b2 = f2bf(acc[mr][nc][2] * sinv);
                unsigned short b3 = f2bf(acc[mr][nc][3] * sinv);
                uint2 v;
                v.x = (unsigned)b0 | ((unsigned)b1 << 16);
                v.y = (unsigned)b2 | ((unsigned)b3 << 16);
                *(uint2*)(rowp + (((unsigned)(32 * mr + 8 * g)) ^ sw)) = v;
            }
        }

        // ---- O = P V : A = P from LDS (row c=li+16mc, k j=32kt+8g+jj), B = Vf ----
        f32x4 o[4][2];
        #pragma unroll
        for (int mc = 0; mc < 4; ++mc)
            #pragma unroll
            for (int nd = 0; nd < 2; ++nd) o[mc][nd] = f32x4{0.f, 0.f, 0.f, 0.f};
        #pragma unroll
        for (int mc = 0; mc < 4; ++mc) {
            int c2 = li + 16 * mc;
            char* rowp = P + c2 * 128;
            unsigned sw = ((unsigned)(c2 & 7)) << 4;
            #pragma unroll
            for (int kt = 0; kt < 2; ++kt) {
                s16x8 pa = *(const s16x8*)(rowp + (((unsigned)(64 * kt + 16 * g)) ^ sw));
                #pragma unroll
                for (int nd = 0; nd < 2; ++nd)
                    o[mc][nd] = __builtin_amdgcn_mfma_f32_16x16x32_bf16(pa, Vf[nd][kt], o[mc][nd], 0, 0, 0);
            }
        }

        // ---- store: out[b][c][h*32 + d], C/D layout rows c = 16mc+4g+i, col d = li+16nd
        float* ob = out + (long)b * (49 * 256) + h * 32;
        #pragma unroll
        for (int mc = 0; mc < 4; ++mc) {
            int cbase = 16 * mc + 4 * g;
            #pragma unroll
            for (int i = 0; i < 4; ++i) {
                int crow = cbase + i;
                if (crow < 49) {
                    #pragma unroll
                    for (int nd = 0; nd < 2; ++nd)
                        ob[(long)crow * 256 + 16 * nd + li] = o[mc][nd][i];
                }
            }
        }
    }
}

extern "C" void kernel_launch(void* const* d_in, const int* in_sizes, int n_in,
                              void* d_out, int out_size, void* d_ws, size_t ws_size,
                              hipStream_t stream) {
    const float* x          = (const float*)d_in[0];
    const float* bias_table = (const float*)d_in[1];
    const float* mask       = (const float*)d_in[2];
    const int*   rel_index  = (const int*)d_in[3];
    float* out   = (float*)d_out;
    float* fused = (float*)d_ws;

    const size_t need = (size_t)512 * 49 * 52 * 4;   // 5.2 MB fused (mask+bias)*log2e
    if (ws_size >= need) {
        const int total = 512 * 2401;
        fuse_bias_mask<<<(total + 255) / 256, 256, 0, stream>>>(bias_table, mask, rel_index, fused);
        win_attn<true><<<4096, 256, 0, stream>>>(x, bias_table, mask, rel_index, fused, out);
    } else {
        win_attn<false><<<4096, 256, 0, stream>>>(x, bias_table, mask, rel_index, nullptr, out);
    }
}